// Round 9
// baseline (166.186 us; speedup 1.0000x reference)
//
#include <hip/hip_runtime.h>
#include <hip/hip_bf16.h>

// Problem: B=2, C=256, H=W=64 -> N=4096 spatial, 8 heads, d=32.
// R15: R14 was neutral -> proj's pbuf re-reads are L3-absorbed; traffic is
// not the issue. qkv/proj both carry TWO 64x264 LDS tiles (67.6KB -> 2
// blocks/CU max; proj grid even capped it at 1). The w-side tile doesn't
// need LDS: each MFMA w-fragment is a row-contiguous 8-elem slice loadable
// directly from L2-resident w (f32->bf16 cvt in regs). R15: qkv drops Bs
// staging (LDS 33.8KB -> 4 blocks/CU, 1 barrier); proj reverts to grid
// (4,4,32) and drops As staging (LDS 33.8KB, 1 barrier). attn byte-identical
// control (expect 65.8us / 43 / 39% / 7.34M unchanged).

typedef __bf16 bf16;
typedef __bf16 bf16x4 __attribute__((ext_vector_type(4)));
typedef __bf16 bf16x8 __attribute__((ext_vector_type(8)));
typedef float  f32x4  __attribute__((ext_vector_type(4)));
typedef short  s16x4  __attribute__((ext_vector_type(4)));

#if __has_builtin(__builtin_amdgcn_mfma_f32_16x16x16bf16_1k)
#define HAVE_MFMA16 1
#endif

#if __has_builtin(__builtin_amdgcn_exp2f)
#define EXP2(x) __builtin_amdgcn_exp2f(x)
#else
#define EXP2(x) exp2f(x)
#endif

#define NS 4096
#define QSCALE (0.17677669529663687f * 1.4426950408889634f)

static __device__ inline unsigned pack2(float a, float b) {
  union { bf16 h[2]; unsigned u; } v;
  v.h[0] = (bf16)a; v.h[1] = (bf16)b;
  return v.u;
}

// ---------------------------------------------------------------------------
// Kernel 1: qkv with fused x-transpose. R15: w fragments loaded DIRECT from
// global (no Bs LDS tile). LDS = As only (33.8KB) -> 4 blocks/CU.
// grid (64 n-tiles, 12 o-tiles, 2), block 256.
// ---------------------------------------------------------------------------
__global__ __launch_bounds__(256) void qkv_fused(
    const float* __restrict__ x, const float* __restrict__ w,
    const float* __restrict__ bias,
    bf16* __restrict__ qbuf, bf16* __restrict__ kbuf, bf16* __restrict__ vbuf)
{
  __shared__ bf16 As[64 * 264];  // x^T tile [n_local][c 0..255]
  const int n0 = blockIdx.x * 64, o0 = blockIdx.y * 64, b = blockIdx.z;
  const int t = threadIdx.x;
  const int wv = t >> 6, L = t & 63, quad = L >> 4, lb = L & 15;

  {
    unsigned* A32 = (unsigned*)As;
    const int nj = (t & 15) * 4;
#pragma unroll
    for (int p = 0; p < 8; p++) {
      const int c = p * 32 + (t >> 4) * 2;
      const float* xr = x + ((size_t)(b * 256 + c)) * NS + n0 + nj;
      f32x4 va = *(const f32x4*)xr;
      f32x4 vb = *(const f32x4*)(xr + NS);
#pragma unroll
      for (int i = 0; i < 4; i++)
        A32[(nj + i) * 132 + (c >> 1)] = pack2(va[i], vb[i]);
    }
  }
  __syncthreads();

  // B-fragment source: row (o0 + wv*16 + lb) of w, cols ks*32 + quad*8 ..+7
  const float* wrow = w + (size_t)(o0 + wv * 16 + lb) * 256 + quad * 8;

  f32x4 acc[4] = {};
#pragma unroll
  for (int ks = 0; ks < 8; ks++) {
    const f32x4 wa = *(const f32x4*)(wrow + ks * 32);
    const f32x4 wb = *(const f32x4*)(wrow + ks * 32 + 4);
    bf16x8 bfr;
#pragma unroll
    for (int i = 0; i < 4; i++) {
      bfr[i] = (bf16)wa[i];
      bfr[4 + i] = (bf16)wb[i];
    }
#pragma unroll
    for (int a = 0; a < 4; a++) {
      const bf16x8 afr = *(const bf16x8*)&As[(a * 16 + lb) * 264 + ks * 32 + quad * 8];
      acc[a] = __builtin_amdgcn_mfma_f32_16x16x32_bf16(afr, bfr, acc[a], 0, 0, 0);
    }
  }

  const int comp = o0 >> 8;
  const int o = o0 + wv * 16 + lb;
  const float bv = bias[o];
  if (comp < 2) {
    bf16* dst = (comp == 0) ? qbuf : kbuf;
    const float sc = (comp == 0) ? QSCALE : 1.0f;
    const int hh = (o & 255) >> 5, dd = o & 31;
    const size_t base = ((size_t)b * 8 + hh) * NS;
#pragma unroll
    for (int a = 0; a < 4; a++)
#pragma unroll
      for (int r = 0; r < 4; r++) {
        const int n = n0 + a * 16 + quad * 4 + r;
        dst[(base + n) * 32 + dd] = (bf16)((acc[a][r] + bv) * sc);
      }
  } else {
    __syncthreads();
    bf16* Vt2 = As;  // reuse: [o_local][n_local], stride 72
#pragma unroll
    for (int a = 0; a < 4; a++)
#pragma unroll
      for (int r = 0; r < 4; r++)
        Vt2[(wv * 16 + lb) * 72 + a * 16 + quad * 4 + r] = (bf16)(acc[a][r] + bv);
    __syncthreads();
    const int row = t & 63;
    const int o2 = o0 + row;
    const int hh2 = (o2 & 255) >> 5, dd2 = o2 & 31;
    const int hc = (t >> 6) * 16;
    bf16x8 v0 = *(const bf16x8*)&Vt2[row * 72 + hc];
    bf16x8 v1 = *(const bf16x8*)&Vt2[row * 72 + hc + 8];
    bf16* vd = vbuf + (((size_t)b * 8 + hh2) * 32 + dd2) * NS + n0 + hc;
    *(bf16x8*)vd = v0;
    *(bf16x8*)(vd + 8) = v1;
  }
}

// ---------------------------------------------------------------------------
// Kernel 2: attn (byte-identical to R13/R14). grid (NS/128, B*8, 4 quarters),
// block 256 (4 waves, 32 q-rows each). Per-bi interleaved inner loop.
// Writes UNNORMALIZED O-partials (f32) and row-sums l (f32).
// ---------------------------------------------------------------------------
#define VT_OFF 2560                 // 64*40
#define KV_SZ  (2560 + 32 * 72)     // + V^T tile [d][kv], stride 72

__global__ __launch_bounds__(256) void attn_kernel(
    const bf16* __restrict__ qbuf, const bf16* __restrict__ kbuf,
    const bf16* __restrict__ vbuf, float* __restrict__ pbuf,
    float* __restrict__ lbuf)
{
  __shared__ bf16 KV[2][KV_SZ];
#ifndef HAVE_MFMA16
  __shared__ bf16 Ps[4][16 * 72];
#endif

  const int qb = blockIdx.x;
  const int bh = blockIdx.y;
  const int part = blockIdx.z;          // kv quarter 0..3
  const int kv0 = part * 1024;
  const bf16* Q  = qbuf + (size_t)bh * NS * 32;
  const bf16* K  = kbuf + (size_t)bh * NS * 32 + (size_t)kv0 * 32;
  const bf16* Vt = vbuf + (size_t)bh * 32 * NS + kv0;

  const int t = threadIdx.x;
  const int wv = t >> 6, L = t & 63, quad = L >> 4, lb = L & 15;
  const int qrow = qb * 128 + wv * 32;  // wave owns q rows [qrow, qrow+32)

  const bf16x8 qfrag0 = *(const bf16x8*)(Q + (size_t)(qrow + lb) * 32 + quad * 8);
  const bf16x8 qfrag1 = *(const bf16x8*)(Q + (size_t)(qrow + 16 + lb) * 32 + quad * 8);

  const int koff = (t >> 2) * 40 + (t & 3) * 8;
  const int voff = VT_OFF + (t >> 3) * 72 + (t & 7) * 8;
  const bf16* gk = K + (size_t)(t >> 2) * 32 + (t & 3) * 8;
  const bf16* gv = Vt + (size_t)(t >> 3) * NS + (t & 7) * 8;

  bf16x8 regk = *(const bf16x8*)gk;
  bf16x8 regv = *(const bf16x8*)gv;

  f32x4 oa0 = {0.f, 0.f, 0.f, 0.f}, oa1 = {0.f, 0.f, 0.f, 0.f};
  f32x4 oa2 = {0.f, 0.f, 0.f, 0.f}, oa3 = {0.f, 0.f, 0.f, 0.f};
  f32x4 oa4 = {0.f, 0.f, 0.f, 0.f}, oa5 = {0.f, 0.f, 0.f, 0.f};
  const f32x4 zero4 = {0.f, 0.f, 0.f, 0.f};
#ifdef HAVE_MFMA16
  const s16x4 ones = {(short)0x3F80, (short)0x3F80, (short)0x3F80, (short)0x3F80};
#else
  float l0_i = 0.f, l1_i = 0.f;
#endif

#pragma unroll 2
  for (int kt = 0; kt < 16; kt++) {
    const int buf = kt & 1;
    *(bf16x8*)&KV[buf][koff] = regk;
    *(bf16x8*)&KV[buf][voff] = regv;
    __syncthreads();
    if (kt < 15) {
      regk = *(const bf16x8*)(gk + (size_t)(kt + 1) * (64 * 32));
      regv = *(const bf16x8*)(gv + (size_t)(kt + 1) * 64);
    }

#ifdef HAVE_MFMA16
#pragma unroll
    for (int bi = 0; bi < 4; bi++) {
      const bf16x8 kf = *(const bf16x8*)&KV[buf][(bi * 16 + lb) * 40 + quad * 8];
      const f32x4 s0 = __builtin_amdgcn_mfma_f32_16x16x32_bf16(kf, qfrag0, zero4, 0, 0, 0);
      const f32x4 s1 = __builtin_amdgcn_mfma_f32_16x16x32_bf16(kf, qfrag1, zero4, 0, 0, 0);
      bf16x4 pb0, pb1;
#pragma unroll
      for (int r = 0; r < 4; r++) {
        pb0[r] = (bf16)EXP2(s0[r]);
        pb1[r] = (bf16)EXP2(s1[r]);
      }
      const s16x4 pf0 = __builtin_bit_cast(s16x4, pb0);
      const s16x4 pf1 = __builtin_bit_cast(s16x4, pb1);
      const s16x4 vf0 = __builtin_bit_cast(s16x4,
          *(const bf16x4*)&KV[buf][VT_OFF + lb * 72 + bi * 16 + quad * 4]);
      const s16x4 vf1 = __builtin_bit_cast(s16x4,
          *(const bf16x4*)&KV[buf][VT_OFF + (16 + lb) * 72 + bi * 16 + quad * 4]);
      oa0 = __builtin_amdgcn_mfma_f32_16x16x16bf16_1k(pf0, vf0, oa0, 0, 0, 0);
      oa1 = __builtin_amdgcn_mfma_f32_16x16x16bf16_1k(pf0, vf1, oa1, 0, 0, 0);
      oa2 = __builtin_amdgcn_mfma_f32_16x16x16bf16_1k(pf0, ones, oa2, 0, 0, 0);
      oa3 = __builtin_amdgcn_mfma_f32_16x16x16bf16_1k(pf1, vf0, oa3, 0, 0, 0);
      oa4 = __builtin_amdgcn_mfma_f32_16x16x16bf16_1k(pf1, vf1, oa4, 0, 0, 0);
      oa5 = __builtin_amdgcn_mfma_f32_16x16x16bf16_1k(pf1, ones, oa5, 0, 0, 0);
    }
#else
    {
      f32x4 st0[4], st1[4];
#pragma unroll
      for (int bi = 0; bi < 4; bi++) {
        const bf16x8 kf = *(const bf16x8*)&KV[buf][(bi * 16 + lb) * 40 + quad * 8];
        st0[bi] = __builtin_amdgcn_mfma_f32_16x16x32_bf16(kf, qfrag0, zero4, 0, 0, 0);
        st1[bi] = __builtin_amdgcn_mfma_f32_16x16x32_bf16(kf, qfrag1, zero4, 0, 0, 0);
      }
#pragma unroll
      for (int bi = 0; bi < 4; bi++)
#pragma unroll
        for (int r = 0; r < 4; r++) {
          st0[bi][r] = EXP2(st0[bi][r]);
          st1[bi][r] = EXP2(st1[bi][r]);
        }
      float ls0 = 0.f, ls1 = 0.f;
#pragma unroll
      for (int bi = 0; bi < 4; bi++)
#pragma unroll
        for (int r = 0; r < 4; r++) { ls0 += st0[bi][r]; ls1 += st1[bi][r]; }
      l0_i += ls0; l1_i += ls1;
      bf16* P = &Ps[wv][0];
#pragma unroll
      for (int bi = 0; bi < 4; bi++) {
        bf16x4 pk;
#pragma unroll
        for (int r = 0; r < 4; r++) pk[r] = (bf16)st0[bi][r];
        *(bf16x4*)&P[lb * 72 + bi * 16 + quad * 4] = pk;
      }
#pragma unroll
      for (int ch = 0; ch < 2; ch++) {
        const bf16x8 pf  = *(const bf16x8*)&P[lb * 72 + ch * 32 + quad * 8];
        const bf16x8 vf0 = *(const bf16x8*)&KV[buf][VT_OFF + lb * 72 + ch * 32 + quad * 8];
        const bf16x8 vf1 = *(const bf16x8*)&KV[buf][VT_OFF + (16 + lb) * 72 + ch * 32 + quad * 8];
        oa0 = __builtin_amdgcn_mfma_f32_16x16x32_bf16(pf, vf0, oa0, 0, 0, 0);
        oa1 = __builtin_amdgcn_mfma_f32_16x16x32_bf16(pf, vf1, oa1, 0, 0, 0);
      }
#pragma unroll
      for (int bi = 0; bi < 4; bi++) {
        bf16x4 pk;
#pragma unroll
        for (int r = 0; r < 4; r++) pk[r] = (bf16)st1[bi][r];
        *(bf16x4*)&P[lb * 72 + bi * 16 + quad * 4] = pk;
      }
#pragma unroll
      for (int ch = 0; ch < 2; ch++) {
        const bf16x8 pf  = *(const bf16x8*)&P[lb * 72 + ch * 32 + quad * 8];
        const bf16x8 vf0 = *(const bf16x8*)&KV[buf][VT_OFF + lb * 72 + ch * 32 + quad * 8];
        const bf16x8 vf1 = *(const bf16x8*)&KV[buf][VT_OFF + (16 + lb) * 72 + ch * 32 + quad * 8];
        oa3 = __builtin_amdgcn_mfma_f32_16x16x32_bf16(pf, vf0, oa3, 0, 0, 0);
        oa4 = __builtin_amdgcn_mfma_f32_16x16x32_bf16(pf, vf1, oa4, 0, 0, 0);
      }
    }
#endif
  }

  // epilogue: write unnormalized partials + l for this kv-quarter.
  const int b_ = bh >> 3;
  const int hh = bh & 7;
  float* pb = pbuf + ((size_t)(part * 2 + b_) * NS) * 256;
  float* lsum = lbuf + ((size_t)(part * 2 + b_) * NS) * 8;
#ifndef HAVE_MFMA16
  float lf0 = l0_i, lf1 = l1_i;
  lf0 += __shfl_xor(lf0, 16); lf0 += __shfl_xor(lf0, 32);
  lf1 += __shfl_xor(lf1, 16); lf1 += __shfl_xor(lf1, 32);
#endif
#pragma unroll
  for (int r = 0; r < 4; r++) {
    const int n0_ = qrow + quad * 4 + r;
    const int n1_ = n0_ + 16;
    float* d0 = pb + (size_t)n0_ * 256 + hh * 32;
    float* d1 = pb + (size_t)n1_ * 256 + hh * 32;
    d0[lb]      = oa0[r];
    d0[16 + lb] = oa1[r];
    d1[lb]      = oa3[r];
    d1[16 + lb] = oa4[r];
#ifdef HAVE_MFMA16
    if (lb == 0) {
      lsum[(size_t)n0_ * 8 + hh] = oa2[r];
      lsum[(size_t)n1_ * 8 + hh] = oa5[r];
    }
#else
    const float lr0 = __shfl(lf0, (quad << 4) | (quad * 4 + r));
    const float lr1 = __shfl(lf1, (quad << 4) | (quad * 4 + r));
    if (lb == 0) {
      lsum[(size_t)n0_ * 8 + hh] = lr0;
      lsum[(size_t)n1_ * 8 + hh] = lr1;
    }
#endif
  }
}

// ---------------------------------------------------------------------------
// Kernel 3: proj with fused a-transpose AND fused 4-way softmax combine.
// R15: w fragments loaded DIRECT from global (no As LDS tile); LDS = Bs only
// (33.8KB); single barrier. grid back to (4, 4, 32 = b*16+sHi), block 256.
// ---------------------------------------------------------------------------
__global__ __launch_bounds__(256) void proj_fused(
    const float* __restrict__ pbuf, const float* __restrict__ lbuf,
    const float* __restrict__ w, const float* __restrict__ bias,
    float* __restrict__ out)
{
  __shared__ bf16 Bs[64 * 264];  // combined-a^T tile [ch_local][c 0..255]
  const int ch0 = blockIdx.x * 64, o0 = blockIdx.y * 64;
  const int z = blockIdx.z, b = z >> 4, sHi = z & 15;
  const int t = threadIdx.x;
  const int wv = t >> 6, L = t & 63, quad = L >> 4, lb = L & 15;

  {
    const int chj = (t & 7) * 8;               // 8-ch chunk, within one head
    const int hh = (ch0 + chj) >> 5;           // head index for this chunk
#pragma unroll
    for (int p = 0; p < 8; p++) {
      const int c = p * 32 + (t >> 3);         // 0..255
      const int n = c * 16 + sHi;              // spatial index
      f32x4 s0 = {0.f, 0.f, 0.f, 0.f}, s1 = {0.f, 0.f, 0.f, 0.f};
      float lt = 0.f;
#pragma unroll
      for (int hq = 0; hq < 4; hq++) {
        const size_t row = (size_t)(hq * 2 + b) * NS + n;
        const float* pp = pbuf + row * 256 + ch0 + chj;
        s0 += *(const f32x4*)pp;
        s1 += *(const f32x4*)(pp + 4);
        lt += lbuf[row * 8 + hh];
      }
      const float inv = 1.0f / lt;
#pragma unroll
      for (int i = 0; i < 4; i++) {
        Bs[(chj + i) * 264 + c]     = (bf16)(s0[i] * inv);
        Bs[(chj + 4 + i) * 264 + c] = (bf16)(s1[i] * inv);
      }
    }
  }
  __syncthreads();

  f32x4 acc[4] = {};
#pragma unroll
  for (int ks = 0; ks < 8; ks++) {
    const bf16x8 bfr = *(const bf16x8*)&Bs[(wv * 16 + lb) * 264 + ks * 32 + quad * 8];
#pragma unroll
    for (int a = 0; a < 4; a++) {
      // w fragment direct: row o0 + a*16 + lb, cols ks*32 + quad*8 ..+7
      const float* wr = w + (size_t)(o0 + a * 16 + lb) * 256 + ks * 32 + quad * 8;
      const f32x4 wa = *(const f32x4*)wr;
      const f32x4 wb = *(const f32x4*)(wr + 4);
      bf16x8 afr;
#pragma unroll
      for (int i = 0; i < 4; i++) {
        afr[i] = (bf16)wa[i];
        afr[4 + i] = (bf16)wb[i];
      }
      acc[a] = __builtin_amdgcn_mfma_f32_16x16x32_bf16(afr, bfr, acc[a], 0, 0, 0);
    }
  }

  const int ch = ch0 + wv * 16 + lb;
#pragma unroll
  for (int a = 0; a < 4; a++)
#pragma unroll
    for (int r = 0; r < 4; r++) {
      const int o = o0 + a * 16 + quad * 4 + r;
      out[((size_t)b * 256 + o) * NS + sHi * 256 + ch] = acc[a][r] + bias[o];
    }
}

// ---------------------------------------------------------------------------
extern "C" void kernel_launch(void* const* d_in, const int* in_sizes, int n_in,
                              void* d_out, int out_size, void* d_ws, size_t ws_size,
                              hipStream_t stream) {
  const float* x      = (const float*)d_in[0];
  const float* w_qkv  = (const float*)d_in[1];
  const float* b_qkv  = (const float*)d_in[2];
  const float* w_proj = (const float*)d_in[3];
  const float* b_proj = (const float*)d_in[4];
  float* out = (float*)d_out;

  char* ws = (char*)d_ws;
  const size_t MB = 1024 * 1024;
  bf16* qbuf  = (bf16*)(ws);            //  4 MB: [bh][n][d] bf16
  bf16* kbuf  = (bf16*)(ws + 4 * MB);   //  4 MB
  bf16* vbuf  = (bf16*)(ws + 8 * MB);   //  4 MB: V^T [bh][d][n]
  float* pbuf = (float*)(ws + 12 * MB); // 32 MB: [part*2+b][n][ch] f32
  float* lbuf = (float*)(ws + 44 * MB); //  1 MB: [part*2+b][n][h] f32

  qkv_fused<<<dim3(64, 12, 2), 256, 0, stream>>>(x, w_qkv, b_qkv, qbuf, kbuf, vbuf);
  attn_kernel<<<dim3(32, 16, 4), 256, 0, stream>>>(qbuf, kbuf, vbuf, pbuf, lbuf);
  proj_fused<<<dim3(4, 4, 32), 256, 0, stream>>>(pbuf, lbuf, w_proj, b_proj, out);
}

// Round 10
// 150.786 us; speedup vs baseline: 1.1021x; 1.1021x over previous
//
#include <hip/hip_runtime.h>
#include <hip/hip_bf16.h>

// Problem: B=2, C=256, H=W=64 -> N=4096 spatial, 8 heads, d=32.
// R16: R15 regressed (+14us, attn control held) -> direct w-loads put L2
// latency inside the MFMA loop. Lesson: raise occupancy WITHOUT moving
// loads into the MFMA dependency chain. qkv carried 67.6KB LDS -> 2
// blocks/CU (grid wants 6). R16 splits qkv's K=256 staging into two
// sequential 128-halves (As-half 16.9KB + Bs-half 17.4KB = 34.3KB -> 4
// blocks/CU, 3 barriers, acc persists, identical numerics/load pattern).
// proj reverted to exact R13 (known baseline). attn byte-identical control.

typedef __bf16 bf16;
typedef __bf16 bf16x4 __attribute__((ext_vector_type(4)));
typedef __bf16 bf16x8 __attribute__((ext_vector_type(8)));
typedef float  f32x4  __attribute__((ext_vector_type(4)));
typedef short  s16x4  __attribute__((ext_vector_type(4)));

#if __has_builtin(__builtin_amdgcn_mfma_f32_16x16x16bf16_1k)
#define HAVE_MFMA16 1
#endif

#if __has_builtin(__builtin_amdgcn_exp2f)
#define EXP2(x) __builtin_amdgcn_exp2f(x)
#else
#define EXP2(x) exp2f(x)
#endif

#define NS 4096
#define QSCALE (0.17677669529663687f * 1.4426950408889634f)

static __device__ inline unsigned pack2(float a, float b) {
  union { bf16 h[2]; unsigned u; } v;
  v.h[0] = (bf16)a; v.h[1] = (bf16)b;
  return v.u;
}

// ---------------------------------------------------------------------------
// Kernel 1: qkv with fused x-transpose, R16 K-split staging.
// Per half h: stage x^T[64][128] + w[64][128] -> barrier -> 4 ks MFMAs.
// LDS 34.3KB -> 4 blocks/CU. grid (64 n-tiles, 12 o-tiles, 2), block 256.
// ---------------------------------------------------------------------------
__global__ __launch_bounds__(256) void qkv_fused(
    const float* __restrict__ x, const float* __restrict__ w,
    const float* __restrict__ bias,
    bf16* __restrict__ qbuf, bf16* __restrict__ kbuf, bf16* __restrict__ vbuf)
{
  __shared__ bf16 As[64 * 132];  // x^T half [n][c_local 0..127 (+4 pad)]
  __shared__ bf16 Bs[64 * 136];  // w half   [o][c_local 0..127 (+8 pad)]
  const int n0 = blockIdx.x * 64, o0 = blockIdx.y * 64, b = blockIdx.z;
  const int t = threadIdx.x;
  const int wv = t >> 6, L = t & 63, quad = L >> 4, lb = L & 15;

  f32x4 acc[4] = {};

#pragma unroll
  for (int h = 0; h < 2; h++) {
    if (h) __syncthreads();      // WAR: half-0 reads done before overwrite
    {
      unsigned* A32 = (unsigned*)As;
      const int nj = (t & 15) * 4;
#pragma unroll
      for (int p = 0; p < 4; p++) {
        const int cl = p * 32 + (t >> 4) * 2;      // 0..126 within half
        const int c = h * 128 + cl;
        const float* xr = x + ((size_t)(b * 256 + c)) * NS + n0 + nj;
        f32x4 va = *(const f32x4*)xr;
        f32x4 vb = *(const f32x4*)(xr + NS);
#pragma unroll
        for (int i = 0; i < 4; i++)
          A32[(nj + i) * 66 + (cl >> 1)] = pack2(va[i], vb[i]);
      }
    }
    {
      const int cj = (t & 7) * 16;                 // 0..112 within half
      const int rbase = t >> 3;                    // 0..31
#pragma unroll
      for (int p = 0; p < 2; p++) {
        const int r = p * 32 + rbase;
        const float* wr = w + (size_t)(o0 + r) * 256 + h * 128 + cj;
        f32x4 w0 = *(const f32x4*)wr,       w1 = *(const f32x4*)(wr + 4);
        f32x4 w2 = *(const f32x4*)(wr + 8), w3 = *(const f32x4*)(wr + 12);
        bf16x8 lo, hi;
#pragma unroll
        for (int i = 0; i < 4; i++) {
          lo[i] = (bf16)w0[i]; lo[4 + i] = (bf16)w1[i];
          hi[i] = (bf16)w2[i]; hi[4 + i] = (bf16)w3[i];
        }
        *(bf16x8*)&Bs[r * 136 + cj] = lo;
        *(bf16x8*)&Bs[r * 136 + cj + 8] = hi;
      }
    }
    __syncthreads();

#pragma unroll
    for (int ks = 0; ks < 4; ks++) {
      const bf16x8 bfr = *(const bf16x8*)&Bs[(wv * 16 + lb) * 136 + ks * 32 + quad * 8];
#pragma unroll
      for (int a = 0; a < 4; a++) {
        const bf16x8 afr = *(const bf16x8*)&As[(a * 16 + lb) * 132 + ks * 32 + quad * 8];
        acc[a] = __builtin_amdgcn_mfma_f32_16x16x32_bf16(afr, bfr, acc[a], 0, 0, 0);
      }
    }
  }

  const int comp = o0 >> 8;
  const int o = o0 + wv * 16 + lb;
  const float bv = bias[o];
  if (comp < 2) {
    bf16* dst = (comp == 0) ? qbuf : kbuf;
    const float sc = (comp == 0) ? QSCALE : 1.0f;
    const int hh = (o & 255) >> 5, dd = o & 31;
    const size_t base = ((size_t)b * 8 + hh) * NS;
#pragma unroll
    for (int a = 0; a < 4; a++)
#pragma unroll
      for (int r = 0; r < 4; r++) {
        const int n = n0 + a * 16 + quad * 4 + r;
        dst[(base + n) * 32 + dd] = (bf16)((acc[a][r] + bv) * sc);
      }
  } else {
    __syncthreads();
    bf16* Vt2 = As;  // reuse: [o_local][n_local], stride 72 (9.2KB <= 16.9KB)
#pragma unroll
    for (int a = 0; a < 4; a++)
#pragma unroll
      for (int r = 0; r < 4; r++)
        Vt2[(wv * 16 + lb) * 72 + a * 16 + quad * 4 + r] = (bf16)(acc[a][r] + bv);
    __syncthreads();
    const int row = t & 63;
    const int o2 = o0 + row;
    const int hh2 = (o2 & 255) >> 5, dd2 = o2 & 31;
    const int hc = (t >> 6) * 16;
    bf16x8 v0 = *(const bf16x8*)&Vt2[row * 72 + hc];
    bf16x8 v1 = *(const bf16x8*)&Vt2[row * 72 + hc + 8];
    bf16* vd = vbuf + (((size_t)b * 8 + hh2) * 32 + dd2) * NS + n0 + hc;
    *(bf16x8*)vd = v0;
    *(bf16x8*)(vd + 8) = v1;
  }
}

// ---------------------------------------------------------------------------
// Kernel 2: attn (byte-identical to R13). grid (NS/128, B*8, 4 quarters),
// block 256 (4 waves, 32 q-rows each). Per-bi interleaved inner loop.
// Writes UNNORMALIZED O-partials (f32) and row-sums l (f32).
// ---------------------------------------------------------------------------
#define VT_OFF 2560                 // 64*40
#define KV_SZ  (2560 + 32 * 72)     // + V^T tile [d][kv], stride 72

__global__ __launch_bounds__(256) void attn_kernel(
    const bf16* __restrict__ qbuf, const bf16* __restrict__ kbuf,
    const bf16* __restrict__ vbuf, float* __restrict__ pbuf,
    float* __restrict__ lbuf)
{
  __shared__ bf16 KV[2][KV_SZ];
#ifndef HAVE_MFMA16
  __shared__ bf16 Ps[4][16 * 72];
#endif

  const int qb = blockIdx.x;
  const int bh = blockIdx.y;
  const int part = blockIdx.z;          // kv quarter 0..3
  const int kv0 = part * 1024;
  const bf16* Q  = qbuf + (size_t)bh * NS * 32;
  const bf16* K  = kbuf + (size_t)bh * NS * 32 + (size_t)kv0 * 32;
  const bf16* Vt = vbuf + (size_t)bh * 32 * NS + kv0;

  const int t = threadIdx.x;
  const int wv = t >> 6, L = t & 63, quad = L >> 4, lb = L & 15;
  const int qrow = qb * 128 + wv * 32;  // wave owns q rows [qrow, qrow+32)

  const bf16x8 qfrag0 = *(const bf16x8*)(Q + (size_t)(qrow + lb) * 32 + quad * 8);
  const bf16x8 qfrag1 = *(const bf16x8*)(Q + (size_t)(qrow + 16 + lb) * 32 + quad * 8);

  const int koff = (t >> 2) * 40 + (t & 3) * 8;
  const int voff = VT_OFF + (t >> 3) * 72 + (t & 7) * 8;
  const bf16* gk = K + (size_t)(t >> 2) * 32 + (t & 3) * 8;
  const bf16* gv = Vt + (size_t)(t >> 3) * NS + (t & 7) * 8;

  bf16x8 regk = *(const bf16x8*)gk;
  bf16x8 regv = *(const bf16x8*)gv;

  f32x4 oa0 = {0.f, 0.f, 0.f, 0.f}, oa1 = {0.f, 0.f, 0.f, 0.f};
  f32x4 oa2 = {0.f, 0.f, 0.f, 0.f}, oa3 = {0.f, 0.f, 0.f, 0.f};
  f32x4 oa4 = {0.f, 0.f, 0.f, 0.f}, oa5 = {0.f, 0.f, 0.f, 0.f};
  const f32x4 zero4 = {0.f, 0.f, 0.f, 0.f};
#ifdef HAVE_MFMA16
  const s16x4 ones = {(short)0x3F80, (short)0x3F80, (short)0x3F80, (short)0x3F80};
#else
  float l0_i = 0.f, l1_i = 0.f;
#endif

#pragma unroll 2
  for (int kt = 0; kt < 16; kt++) {
    const int buf = kt & 1;
    *(bf16x8*)&KV[buf][koff] = regk;
    *(bf16x8*)&KV[buf][voff] = regv;
    __syncthreads();
    if (kt < 15) {
      regk = *(const bf16x8*)(gk + (size_t)(kt + 1) * (64 * 32));
      regv = *(const bf16x8*)(gv + (size_t)(kt + 1) * 64);
    }

#ifdef HAVE_MFMA16
#pragma unroll
    for (int bi = 0; bi < 4; bi++) {
      const bf16x8 kf = *(const bf16x8*)&KV[buf][(bi * 16 + lb) * 40 + quad * 8];
      const f32x4 s0 = __builtin_amdgcn_mfma_f32_16x16x32_bf16(kf, qfrag0, zero4, 0, 0, 0);
      const f32x4 s1 = __builtin_amdgcn_mfma_f32_16x16x32_bf16(kf, qfrag1, zero4, 0, 0, 0);
      bf16x4 pb0, pb1;
#pragma unroll
      for (int r = 0; r < 4; r++) {
        pb0[r] = (bf16)EXP2(s0[r]);
        pb1[r] = (bf16)EXP2(s1[r]);
      }
      const s16x4 pf0 = __builtin_bit_cast(s16x4, pb0);
      const s16x4 pf1 = __builtin_bit_cast(s16x4, pb1);
      const s16x4 vf0 = __builtin_bit_cast(s16x4,
          *(const bf16x4*)&KV[buf][VT_OFF + lb * 72 + bi * 16 + quad * 4]);
      const s16x4 vf1 = __builtin_bit_cast(s16x4,
          *(const bf16x4*)&KV[buf][VT_OFF + (16 + lb) * 72 + bi * 16 + quad * 4]);
      oa0 = __builtin_amdgcn_mfma_f32_16x16x16bf16_1k(pf0, vf0, oa0, 0, 0, 0);
      oa1 = __builtin_amdgcn_mfma_f32_16x16x16bf16_1k(pf0, vf1, oa1, 0, 0, 0);
      oa2 = __builtin_amdgcn_mfma_f32_16x16x16bf16_1k(pf0, ones, oa2, 0, 0, 0);
      oa3 = __builtin_amdgcn_mfma_f32_16x16x16bf16_1k(pf1, vf0, oa3, 0, 0, 0);
      oa4 = __builtin_amdgcn_mfma_f32_16x16x16bf16_1k(pf1, vf1, oa4, 0, 0, 0);
      oa5 = __builtin_amdgcn_mfma_f32_16x16x16bf16_1k(pf1, ones, oa5, 0, 0, 0);
    }
#else
    {
      f32x4 st0[4], st1[4];
#pragma unroll
      for (int bi = 0; bi < 4; bi++) {
        const bf16x8 kf = *(const bf16x8*)&KV[buf][(bi * 16 + lb) * 40 + quad * 8];
        st0[bi] = __builtin_amdgcn_mfma_f32_16x16x32_bf16(kf, qfrag0, zero4, 0, 0, 0);
        st1[bi] = __builtin_amdgcn_mfma_f32_16x16x32_bf16(kf, qfrag1, zero4, 0, 0, 0);
      }
#pragma unroll
      for (int bi = 0; bi < 4; bi++)
#pragma unroll
        for (int r = 0; r < 4; r++) {
          st0[bi][r] = EXP2(st0[bi][r]);
          st1[bi][r] = EXP2(st1[bi][r]);
        }
      float ls0 = 0.f, ls1 = 0.f;
#pragma unroll
      for (int bi = 0; bi < 4; bi++)
#pragma unroll
        for (int r = 0; r < 4; r++) { ls0 += st0[bi][r]; ls1 += st1[bi][r]; }
      l0_i += ls0; l1_i += ls1;
      bf16* P = &Ps[wv][0];
#pragma unroll
      for (int bi = 0; bi < 4; bi++) {
        bf16x4 pk;
#pragma unroll
        for (int r = 0; r < 4; r++) pk[r] = (bf16)st0[bi][r];
        *(bf16x4*)&P[lb * 72 + bi * 16 + quad * 4] = pk;
      }
#pragma unroll
      for (int ch = 0; ch < 2; ch++) {
        const bf16x8 pf  = *(const bf16x8*)&P[lb * 72 + ch * 32 + quad * 8];
        const bf16x8 vf0 = *(const bf16x8*)&KV[buf][VT_OFF + lb * 72 + ch * 32 + quad * 8];
        const bf16x8 vf1 = *(const bf16x8*)&KV[buf][VT_OFF + (16 + lb) * 72 + ch * 32 + quad * 8];
        oa0 = __builtin_amdgcn_mfma_f32_16x16x32_bf16(pf, vf0, oa0, 0, 0, 0);
        oa1 = __builtin_amdgcn_mfma_f32_16x16x32_bf16(pf, vf1, oa1, 0, 0, 0);
      }
#pragma unroll
      for (int bi = 0; bi < 4; bi++) {
        bf16x4 pk;
#pragma unroll
        for (int r = 0; r < 4; r++) pk[r] = (bf16)st1[bi][r];
        *(bf16x4*)&P[lb * 72 + bi * 16 + quad * 4] = pk;
      }
#pragma unroll
      for (int ch = 0; ch < 2; ch++) {
        const bf16x8 pf  = *(const bf16x8*)&P[lb * 72 + ch * 32 + quad * 8];
        const bf16x8 vf0 = *(const bf16x8*)&KV[buf][VT_OFF + lb * 72 + ch * 32 + quad * 8];
        const bf16x8 vf1 = *(const bf16x8*)&KV[buf][VT_OFF + (16 + lb) * 72 + ch * 32 + quad * 8];
        oa3 = __builtin_amdgcn_mfma_f32_16x16x32_bf16(pf, vf0, oa3, 0, 0, 0);
        oa4 = __builtin_amdgcn_mfma_f32_16x16x32_bf16(pf, vf1, oa4, 0, 0, 0);
      }
    }
#endif
  }

  // epilogue: write unnormalized partials + l for this kv-quarter.
  const int b_ = bh >> 3;
  const int hh = bh & 7;
  float* pb = pbuf + ((size_t)(part * 2 + b_) * NS) * 256;
  float* lsum = lbuf + ((size_t)(part * 2 + b_) * NS) * 8;
#ifndef HAVE_MFMA16
  float lf0 = l0_i, lf1 = l1_i;
  lf0 += __shfl_xor(lf0, 16); lf0 += __shfl_xor(lf0, 32);
  lf1 += __shfl_xor(lf1, 16); lf1 += __shfl_xor(lf1, 32);
#endif
#pragma unroll
  for (int r = 0; r < 4; r++) {
    const int n0_ = qrow + quad * 4 + r;
    const int n1_ = n0_ + 16;
    float* d0 = pb + (size_t)n0_ * 256 + hh * 32;
    float* d1 = pb + (size_t)n1_ * 256 + hh * 32;
    d0[lb]      = oa0[r];
    d0[16 + lb] = oa1[r];
    d1[lb]      = oa3[r];
    d1[16 + lb] = oa4[r];
#ifdef HAVE_MFMA16
    if (lb == 0) {
      lsum[(size_t)n0_ * 8 + hh] = oa2[r];
      lsum[(size_t)n1_ * 8 + hh] = oa5[r];
    }
#else
    const float lr0 = __shfl(lf0, (quad << 4) | (quad * 4 + r));
    const float lr1 = __shfl(lf1, (quad << 4) | (quad * 4 + r));
    if (lb == 0) {
      lsum[(size_t)n0_ * 8 + hh] = lr0;
      lsum[(size_t)n1_ * 8 + hh] = lr1;
    }
#endif
  }
}

// ---------------------------------------------------------------------------
// Kernel 3: proj (exact R13): fused a-transpose AND fused 4-way softmax
// combine: Bs = (P0+P1+P2+P3)/(l0+l1+l2+l3) -> bf16 during staging.
// grid (4 ch-tiles, 4 o-tiles, 32 = b*16+sHi), block 256.
// ---------------------------------------------------------------------------
__global__ __launch_bounds__(256) void proj_fused(
    const float* __restrict__ pbuf, const float* __restrict__ lbuf,
    const float* __restrict__ w, const float* __restrict__ bias,
    float* __restrict__ out)
{
  __shared__ bf16 As[64 * 264];  // w tile [o_local][c 0..255]
  __shared__ bf16 Bs[64 * 264];  // combined-a^T tile [ch_local][c 0..255]
  const int ch0 = blockIdx.x * 64, o0 = blockIdx.y * 64;
  const int z = blockIdx.z, b = z >> 4, sHi = z & 15;
  const int t = threadIdx.x;
  const int wv = t >> 6, L = t & 63, quad = L >> 4, lb = L & 15;

  {
    const int cj = (t & 15) * 16;
#pragma unroll
    for (int p = 0; p < 4; p++) {
      const int r = p * 16 + (t >> 4);
      const float* wr = w + (size_t)(o0 + r) * 256 + cj;
      f32x4 w0 = *(const f32x4*)wr,       w1 = *(const f32x4*)(wr + 4);
      f32x4 w2 = *(const f32x4*)(wr + 8), w3 = *(const f32x4*)(wr + 12);
      bf16x8 lo, hi;
#pragma unroll
      for (int i = 0; i < 4; i++) {
        lo[i] = (bf16)w0[i]; lo[4 + i] = (bf16)w1[i];
        hi[i] = (bf16)w2[i]; hi[4 + i] = (bf16)w3[i];
      }
      *(bf16x8*)&As[r * 264 + cj] = lo;
      *(bf16x8*)&As[r * 264 + cj + 8] = hi;
    }
  }
  {
    const int chj = (t & 7) * 8;               // 8-ch chunk, within one head
    const int hh = (ch0 + chj) >> 5;           // head index for this chunk
#pragma unroll
    for (int p = 0; p < 8; p++) {
      const int c = p * 32 + (t >> 3);         // 0..255
      const int n = c * 16 + sHi;              // spatial index
      f32x4 s0 = {0.f, 0.f, 0.f, 0.f}, s1 = {0.f, 0.f, 0.f, 0.f};
      float lt = 0.f;
#pragma unroll
      for (int hq = 0; hq < 4; hq++) {
        const size_t row = (size_t)(hq * 2 + b) * NS + n;
        const float* pp = pbuf + row * 256 + ch0 + chj;
        s0 += *(const f32x4*)pp;
        s1 += *(const f32x4*)(pp + 4);
        lt += lbuf[row * 8 + hh];
      }
      const float inv = 1.0f / lt;
#pragma unroll
      for (int i = 0; i < 4; i++) {
        Bs[(chj + i) * 264 + c]     = (bf16)(s0[i] * inv);
        Bs[(chj + 4 + i) * 264 + c] = (bf16)(s1[i] * inv);
      }
    }
  }
  __syncthreads();

  f32x4 acc[4] = {};
#pragma unroll
  for (int ks = 0; ks < 8; ks++) {
    const bf16x8 bfr = *(const bf16x8*)&Bs[(wv * 16 + lb) * 264 + ks * 32 + quad * 8];
#pragma unroll
    for (int a = 0; a < 4; a++) {
      const bf16x8 afr = *(const bf16x8*)&As[(a * 16 + lb) * 264 + ks * 32 + quad * 8];
      acc[a] = __builtin_amdgcn_mfma_f32_16x16x32_bf16(afr, bfr, acc[a], 0, 0, 0);
    }
  }

  const int ch = ch0 + wv * 16 + lb;
#pragma unroll
  for (int a = 0; a < 4; a++)
#pragma unroll
    for (int r = 0; r < 4; r++) {
      const int o = o0 + a * 16 + quad * 4 + r;
      out[((size_t)b * 256 + o) * NS + sHi * 256 + ch] = acc[a][r] + bias[o];
    }
}

// ---------------------------------------------------------------------------
extern "C" void kernel_launch(void* const* d_in, const int* in_sizes, int n_in,
                              void* d_out, int out_size, void* d_ws, size_t ws_size,
                              hipStream_t stream) {
  const float* x      = (const float*)d_in[0];
  const float* w_qkv  = (const float*)d_in[1];
  const float* b_qkv  = (const float*)d_in[2];
  const float* w_proj = (const float*)d_in[3];
  const float* b_proj = (const float*)d_in[4];
  float* out = (float*)d_out;

  char* ws = (char*)d_ws;
  const size_t MB = 1024 * 1024;
  bf16* qbuf  = (bf16*)(ws);            //  4 MB: [bh][n][d] bf16
  bf16* kbuf  = (bf16*)(ws + 4 * MB);   //  4 MB
  bf16* vbuf  = (bf16*)(ws + 8 * MB);   //  4 MB: V^T [bh][d][n]
  float* pbuf = (float*)(ws + 12 * MB); // 32 MB: [part*2+b][n][ch] f32
  float* lbuf = (float*)(ws + 44 * MB); //  1 MB: [part*2+b][n][h] f32

  qkv_fused<<<dim3(64, 12, 2), 256, 0, stream>>>(x, w_qkv, b_qkv, qbuf, kbuf, vbuf);
  attn_kernel<<<dim3(32, 16, 4), 256, 0, stream>>>(qbuf, kbuf, vbuf, pbuf, lbuf);
  proj_fused<<<dim3(4, 4, 32), 256, 0, stream>>>(pbuf, lbuf, w_proj, b_proj, out);
}